// Round 9
// baseline (136.403 us; speedup 1.0000x reference)
//
#include <hip/hip_runtime.h>

// Problem constants (from reference): B=8, L=4096, D=2048, P=4, S=4, R=32
#define BB 8
#define LL 4096
#define DD 2048
#define PP 4
#define SS 4
#define RR 32

#define N4 ((long long)BB * LL * DD / 4)   // 67,108,864 float4 elements

// Native clang vector type.
typedef float f32x4 __attribute__((ext_vector_type(4)));

// Lean streaming copy: 8 outstanding lane-contiguous 16B loads per wave,
// low VGPR (8 waves/SIMD), persistent grid. Loads cached (MALL keeps
// ~137 MB resident across replays -> halves HBM fetch). Stores REGULAR
// this round (A/B vs round 8's nontemporal): the harness's fillBuffer
// sustains 6.9 TB/s through the cached-store path, while our nt stores
// managed only ~2.4 TB/s effective.
__global__ __launch_bounds__(256) void copy_kernel(
    const f32x4* __restrict__ in, f32x4* __restrict__ out)
{
    const int tid = threadIdx.x;
    long long base = (long long)blockIdx.x * (256 * 8) + tid;
    const long long stride = (long long)gridDim.x * (256 * 8);
    for (; base < N4; base += stride) {
        f32x4 v[8];
#pragma unroll
        for (int k = 0; k < 8; ++k)
            v[k] = in[base + (long long)k * 256];
#pragma unroll
        for (int k = 0; k < 8; ++k)
            out[base + (long long)k * 256] = v[k];
    }
}

// Compute the 64 adapted rows and overwrite them in out (after the copy).
// One block per (b, n); 256 threads; thread t owns columns i = t*8 .. t*8+7.
__global__ __launch_bounds__(256) void adapt_kernel(
    const float* __restrict__ hidden,
    const float* __restrict__ proj_w,   // [8][2048][32]
    const float* __restrict__ src_w,    // [8][2048][32]
    const float* __restrict__ src_bias, // [32]
    const int*   __restrict__ seqlens,  // [8]
    float* __restrict__ out)
{
    const int b = blockIdx.x >> 3;
    const int n = blockIdx.x & 7;
    const int row = (n < PP) ? n : (seqlens[b] - SS + (n - PP));

    const float* x  = hidden + ((size_t)b * LL + row) * DD;
    const float* wp = proj_w + (size_t)n * DD * RR;
    const float* ws = src_w  + (size_t)n * DD * RR;

    const int tid = threadIdx.x;
    const int i0  = tid * 8;

    float xv[8];
    {
        const float4* px = (const float4*)(x + i0);
        float4 a = px[0], c = px[1];
        xv[0] = a.x; xv[1] = a.y; xv[2] = a.z; xv[3] = a.w;
        xv[4] = c.x; xv[5] = c.y; xv[6] = c.z; xv[7] = c.w;
    }

    float pP[RR], pS[RR];
#pragma unroll
    for (int o = 0; o < RR; ++o) { pP[o] = 0.f; pS[o] = 0.f; }

#pragma unroll
    for (int k = 0; k < 8; ++k) {
        const float4* wpr = (const float4*)(wp + (size_t)(i0 + k) * RR);
        const float4* wsr = (const float4*)(ws + (size_t)(i0 + k) * RR);
        const float xi = xv[k];
#pragma unroll
        for (int q = 0; q < 8; ++q) {
            float4 a = wpr[q];
            pP[q*4+0] += xi * a.x; pP[q*4+1] += xi * a.y;
            pP[q*4+2] += xi * a.z; pP[q*4+3] += xi * a.w;
            float4 s = wsr[q];
            pS[q*4+0] += xi * s.x; pS[q*4+1] += xi * s.y;
            pS[q*4+2] += xi * s.z; pS[q*4+3] += xi * s.w;
        }
    }

#pragma unroll
    for (int off = 32; off >= 1; off >>= 1) {
#pragma unroll
        for (int o = 0; o < RR; ++o) {
            pP[o] += __shfl_down(pP[o], off);
            pS[o] += __shfl_down(pS[o], off);
        }
    }

    __shared__ float ldsP[4][RR];
    __shared__ float ldsS[4][RR];
    __shared__ float delta[RR];
    const int wave = tid >> 6;
    const int lane = tid & 63;
    if (lane == 0) {
#pragma unroll
        for (int o = 0; o < RR; ++o) { ldsP[wave][o] = pP[o]; ldsS[wave][o] = pS[o]; }
    }
    __syncthreads();
    if (tid < RR) {
        float sp = ldsP[0][tid] + ldsP[1][tid] + ldsP[2][tid] + ldsP[3][tid];
        float ss = ldsS[0][tid] + ldsS[1][tid] + ldsS[2][tid] + ldsS[3][tid] + src_bias[tid];
        ss = ss > 0.f ? ss : 0.f;              // relu(source)
        delta[tid] = ss - sp;                  // source - projected
    }
    __syncthreads();

    float dl[RR];
#pragma unroll
    for (int o = 0; o < RR; ++o) dl[o] = delta[o];

    float* orow = out + ((size_t)b * LL + row) * DD;
    float res[8];
#pragma unroll
    for (int k = 0; k < 8; ++k) {
        const float4* wpr = (const float4*)(wp + (size_t)(i0 + k) * RR);
        float acc = xv[k];
#pragma unroll
        for (int q = 0; q < 8; ++q) {
            float4 a = wpr[q];
            acc += dl[q*4+0] * a.x + dl[q*4+1] * a.y
                 + dl[q*4+2] * a.z + dl[q*4+3] * a.w;
        }
        res[k] = acc;
    }
    ((float4*)(orow + i0))[0] = make_float4(res[0], res[1], res[2], res[3]);
    ((float4*)(orow + i0))[1] = make_float4(res[4], res[5], res[6], res[7]);
}

extern "C" void kernel_launch(void* const* d_in, const int* in_sizes, int n_in,
                              void* d_out, int out_size, void* d_ws, size_t ws_size,
                              hipStream_t stream) {
    const float* hidden   = (const float*)d_in[0];
    const float* proj_w   = (const float*)d_in[1];
    const float* src_w    = (const float*)d_in[2];
    const float* src_bias = (const float*)d_in[3];
    const int*   seqlens  = (const int*)d_in[4];
    float* out            = (float*)d_out;

    copy_kernel<<<2048, 256, 0, stream>>>((const f32x4*)hidden, (f32x4*)out);
    adapt_kernel<<<BB * (PP + SS), 256, 0, stream>>>(hidden, proj_w, src_w,
                                                     src_bias, seqlens, out);
}

// Round 10
// 118.504 us; speedup vs baseline: 1.1510x; 1.1510x over previous
//
#include <hip/hip_runtime.h>

// Problem constants (from reference): B=8, L=4096, D=2048, P=4, S=4, R=32
#define BB 8
#define LL 4096
#define DD 2048
#define PP 4
#define SS 4
#define RR 32

#define N4 ((long long)BB * LL * DD / 4)   // 67,108,864 float4 elements

// Native clang vector type.
typedef float f32x4 __attribute__((ext_vector_type(4)));

// Streaming copy, 16 outstanding 16B loads per wave before any store-wait
// (double round 8's 8): breaks the per-iteration load->store->drain cycle
// (register reuse forced a full vmcnt drain every 8 chunks). ~72 VGPR ->
// still ~28 waves/CU. Loads cached (MALL keeps ~137 MB resident across
// replays); stores nontemporal (round 9 A/B: regular stores fight reads
// in L2, +19 us).
__global__ __launch_bounds__(256) void copy_kernel(
    const f32x4* __restrict__ in, f32x4* __restrict__ out)
{
    const int tid = threadIdx.x;
    long long base = (long long)blockIdx.x * (256 * 16) + tid;
    const long long stride = (long long)gridDim.x * (256 * 16);
    for (; base < N4; base += stride) {
        f32x4 v[16];
#pragma unroll
        for (int k = 0; k < 16; ++k)
            v[k] = in[base + (long long)k * 256];
#pragma unroll
        for (int k = 0; k < 16; ++k)
            __builtin_nontemporal_store(v[k], &out[base + (long long)k * 256]);
    }
}

// Compute the 64 adapted rows and overwrite them in out (after the copy).
// One block per (b, n); 256 threads; thread t owns columns i = t*8 .. t*8+7.
__global__ __launch_bounds__(256) void adapt_kernel(
    const float* __restrict__ hidden,
    const float* __restrict__ proj_w,   // [8][2048][32]
    const float* __restrict__ src_w,    // [8][2048][32]
    const float* __restrict__ src_bias, // [32]
    const int*   __restrict__ seqlens,  // [8]
    float* __restrict__ out)
{
    const int b = blockIdx.x >> 3;
    const int n = blockIdx.x & 7;
    const int row = (n < PP) ? n : (seqlens[b] - SS + (n - PP));

    const float* x  = hidden + ((size_t)b * LL + row) * DD;
    const float* wp = proj_w + (size_t)n * DD * RR;
    const float* ws = src_w  + (size_t)n * DD * RR;

    const int tid = threadIdx.x;
    const int i0  = tid * 8;

    float xv[8];
    {
        const float4* px = (const float4*)(x + i0);
        float4 a = px[0], c = px[1];
        xv[0] = a.x; xv[1] = a.y; xv[2] = a.z; xv[3] = a.w;
        xv[4] = c.x; xv[5] = c.y; xv[6] = c.z; xv[7] = c.w;
    }

    float pP[RR], pS[RR];
#pragma unroll
    for (int o = 0; o < RR; ++o) { pP[o] = 0.f; pS[o] = 0.f; }

#pragma unroll
    for (int k = 0; k < 8; ++k) {
        const float4* wpr = (const float4*)(wp + (size_t)(i0 + k) * RR);
        const float4* wsr = (const float4*)(ws + (size_t)(i0 + k) * RR);
        const float xi = xv[k];
#pragma unroll
        for (int q = 0; q < 8; ++q) {
            float4 a = wpr[q];
            pP[q*4+0] += xi * a.x; pP[q*4+1] += xi * a.y;
            pP[q*4+2] += xi * a.z; pP[q*4+3] += xi * a.w;
            float4 s = wsr[q];
            pS[q*4+0] += xi * s.x; pS[q*4+1] += xi * s.y;
            pS[q*4+2] += xi * s.z; pS[q*4+3] += xi * s.w;
        }
    }

#pragma unroll
    for (int off = 32; off >= 1; off >>= 1) {
#pragma unroll
        for (int o = 0; o < RR; ++o) {
            pP[o] += __shfl_down(pP[o], off);
            pS[o] += __shfl_down(pS[o], off);
        }
    }

    __shared__ float ldsP[4][RR];
    __shared__ float ldsS[4][RR];
    __shared__ float delta[RR];
    const int wave = tid >> 6;
    const int lane = tid & 63;
    if (lane == 0) {
#pragma unroll
        for (int o = 0; o < RR; ++o) { ldsP[wave][o] = pP[o]; ldsS[wave][o] = pS[o]; }
    }
    __syncthreads();
    if (tid < RR) {
        float sp = ldsP[0][tid] + ldsP[1][tid] + ldsP[2][tid] + ldsP[3][tid];
        float ss = ldsS[0][tid] + ldsS[1][tid] + ldsS[2][tid] + ldsS[3][tid] + src_bias[tid];
        ss = ss > 0.f ? ss : 0.f;              // relu(source)
        delta[tid] = ss - sp;                  // source - projected
    }
    __syncthreads();

    float dl[RR];
#pragma unroll
    for (int o = 0; o < RR; ++o) dl[o] = delta[o];

    float* orow = out + ((size_t)b * LL + row) * DD;
    float res[8];
#pragma unroll
    for (int k = 0; k < 8; ++k) {
        const float4* wpr = (const float4*)(wp + (size_t)(i0 + k) * RR);
        float acc = xv[k];
#pragma unroll
        for (int q = 0; q < 8; ++q) {
            float4 a = wpr[q];
            acc += dl[q*4+0] * a.x + dl[q*4+1] * a.y
                 + dl[q*4+2] * a.z + dl[q*4+3] * a.w;
        }
        res[k] = acc;
    }
    ((float4*)(orow + i0))[0] = make_float4(res[0], res[1], res[2], res[3]);
    ((float4*)(orow + i0))[1] = make_float4(res[4], res[5], res[6], res[7]);
}

extern "C" void kernel_launch(void* const* d_in, const int* in_sizes, int n_in,
                              void* d_out, int out_size, void* d_ws, size_t ws_size,
                              hipStream_t stream) {
    const float* hidden   = (const float*)d_in[0];
    const float* proj_w   = (const float*)d_in[1];
    const float* src_w    = (const float*)d_in[2];
    const float* src_bias = (const float*)d_in[3];
    const int*   seqlens  = (const int*)d_in[4];
    float* out            = (float*)d_out;

    copy_kernel<<<2048, 256, 0, stream>>>((const f32x4*)hidden, (f32x4*)out);
    adapt_kernel<<<BB * (PP + SS), 256, 0, stream>>>(hidden, proj_w, src_w,
                                                     src_bias, seqlens, out);
}

// Round 11
// 87.038 us; speedup vs baseline: 1.5672x; 1.3615x over previous
//
#include <hip/hip_runtime.h>

// Problem constants (from reference): B=8, L=4096, D=2048, P=4, S=4, R=32
#define BB 8
#define LL 4096
#define DD 2048
#define PP 4
#define SS 4
#define RR 32

#define N4 ((long long)BB * LL * DD / 4)   // 67,108,864 float4 elements
#define ADAPT_BLOCKS (BB * (PP + SS))      // 64
#define COPY_BLOCKS  2048

// Native clang vector type.
typedef float f32x4 __attribute__((ext_vector_type(4)));

// Single dispatch:
//   blocks 0..63        : rank-32 adapter for the 64 special rows
//   blocks 64..64+2047  : streaming copy (8-deep ILP, cached loads, nt stores)
//                         that SKIPS stores to adapted rows (disjoint writes,
//                         so adapter runs concurrently instead of serialized).
__global__ __launch_bounds__(256) void fused_kernel(
    const float* __restrict__ hidden,
    const float* __restrict__ proj_w,   // [8][2048][32]
    const float* __restrict__ src_w,    // [8][2048][32]
    const float* __restrict__ src_bias, // [32]
    const int*   __restrict__ seqlens,  // [8]
    float* __restrict__ out)
{
    const int tid = threadIdx.x;

    if (blockIdx.x >= ADAPT_BLOCKS) {
        // ---------------- streaming copy path ----------------
        const int cb = blockIdx.x - ADAPT_BLOCKS;
        // seqlens as two int4s; per-chunk select via cndmask tree (no
        // runtime-indexed array -> no scratch).
        const int4 sA = *(const int4*)seqlens;        // sl[0..3]
        const int4 sB = *(const int4*)(seqlens + 4);  // sl[4..7]

        long long base = (long long)cb * (256 * 8) + tid;
        const long long stride = (long long)COPY_BLOCKS * (256 * 8);
        for (; base < N4; base += stride) {
            f32x4 v[8];
#pragma unroll
            for (int k = 0; k < 8; ++k)
                v[k] = ((const f32x4*)hidden)[base + (long long)k * 256];
#pragma unroll
            for (int k = 0; k < 8; ++k) {
                const long long idx = base + (long long)k * 256;
                const int r  = (int)((idx >> 9) & (LL - 1));   // row within batch
                const int bt = (int)(idx >> 21);               // batch
                const int sab = (bt & 2) ? ((bt & 1) ? sA.w : sA.z)
                                         : ((bt & 1) ? sA.y : sA.x);
                const int scd = (bt & 2) ? ((bt & 1) ? sB.w : sB.z)
                                         : ((bt & 1) ? sB.y : sB.x);
                const int sl  = (bt & 4) ? scd : sab;
                const bool adapted = (r < PP) | ((unsigned)(r - (sl - SS)) < (unsigned)SS);
                if (!adapted)
                    __builtin_nontemporal_store(v[k], &((f32x4*)out)[idx]);
            }
        }
        return;
    }

    // ---------------- adapter path (blocks 0..63) ----------------
    const int b = blockIdx.x >> 3;
    const int n = blockIdx.x & 7;
    const int row = (n < PP) ? n : (seqlens[b] - SS + (n - PP));

    const float* x  = hidden + ((size_t)b * LL + row) * DD;
    const float* wp = proj_w + (size_t)n * DD * RR;
    const float* ws = src_w  + (size_t)n * DD * RR;

    const int i0 = tid * 8;

    float xv[8];
    {
        const float4* px = (const float4*)(x + i0);
        float4 a = px[0], c = px[1];
        xv[0] = a.x; xv[1] = a.y; xv[2] = a.z; xv[3] = a.w;
        xv[4] = c.x; xv[5] = c.y; xv[6] = c.z; xv[7] = c.w;
    }

    float pP[RR], pS[RR];
#pragma unroll
    for (int o = 0; o < RR; ++o) { pP[o] = 0.f; pS[o] = 0.f; }

#pragma unroll
    for (int k = 0; k < 8; ++k) {
        const float4* wpr = (const float4*)(wp + (size_t)(i0 + k) * RR);
        const float4* wsr = (const float4*)(ws + (size_t)(i0 + k) * RR);
        const float xi = xv[k];
#pragma unroll
        for (int q = 0; q < 8; ++q) {
            float4 a = wpr[q];
            pP[q*4+0] += xi * a.x; pP[q*4+1] += xi * a.y;
            pP[q*4+2] += xi * a.z; pP[q*4+3] += xi * a.w;
            float4 s = wsr[q];
            pS[q*4+0] += xi * s.x; pS[q*4+1] += xi * s.y;
            pS[q*4+2] += xi * s.z; pS[q*4+3] += xi * s.w;
        }
    }

#pragma unroll
    for (int off = 32; off >= 1; off >>= 1) {
#pragma unroll
        for (int o = 0; o < RR; ++o) {
            pP[o] += __shfl_down(pP[o], off);
            pS[o] += __shfl_down(pS[o], off);
        }
    }

    __shared__ float ldsP[4][RR];
    __shared__ float ldsS[4][RR];
    __shared__ float delta[RR];
    const int wave = tid >> 6;
    const int lane = tid & 63;
    if (lane == 0) {
#pragma unroll
        for (int o = 0; o < RR; ++o) { ldsP[wave][o] = pP[o]; ldsS[wave][o] = pS[o]; }
    }
    __syncthreads();
    if (tid < RR) {
        float sp = ldsP[0][tid] + ldsP[1][tid] + ldsP[2][tid] + ldsP[3][tid];
        float ss = ldsS[0][tid] + ldsS[1][tid] + ldsS[2][tid] + ldsS[3][tid] + src_bias[tid];
        ss = ss > 0.f ? ss : 0.f;              // relu(source)
        delta[tid] = ss - sp;                  // source - projected
    }
    __syncthreads();

    float dl[RR];
#pragma unroll
    for (int o = 0; o < RR; ++o) dl[o] = delta[o];

    float* orow = out + ((size_t)b * LL + row) * DD;
    float res[8];
#pragma unroll
    for (int k = 0; k < 8; ++k) {
        const float4* wpr = (const float4*)(wp + (size_t)(i0 + k) * RR);
        float acc = xv[k];
#pragma unroll
        for (int q = 0; q < 8; ++q) {
            float4 a = wpr[q];
            acc += dl[q*4+0] * a.x + dl[q*4+1] * a.y
                 + dl[q*4+2] * a.z + dl[q*4+3] * a.w;
        }
        res[k] = acc;
    }
    ((float4*)(orow + i0))[0] = make_float4(res[0], res[1], res[2], res[3]);
    ((float4*)(orow + i0))[1] = make_float4(res[4], res[5], res[6], res[7]);
}

extern "C" void kernel_launch(void* const* d_in, const int* in_sizes, int n_in,
                              void* d_out, int out_size, void* d_ws, size_t ws_size,
                              hipStream_t stream) {
    const float* hidden   = (const float*)d_in[0];
    const float* proj_w   = (const float*)d_in[1];
    const float* src_w    = (const float*)d_in[2];
    const float* src_bias = (const float*)d_in[3];
    const int*   seqlens  = (const int*)d_in[4];
    float* out            = (float*)d_out;

    fused_kernel<<<ADAPT_BLOCKS + COPY_BLOCKS, 256, 0, stream>>>(
        hidden, proj_w, src_w, src_bias, seqlens, out);
}